// Round 4
// baseline (215.001 us; speedup 1.0000x reference)
//
#include <hip/hip_runtime.h>
#include <float.h>

// VQ-VAE vector quantizer forward, MI355X fp32 — single fused kernel.
// x: [B=32, C=64, H=64, W=64] fp32; emb: [K=512, D=64] fp32.
// out flat (b, h*w, c): out[g*64 + c] = emb[argmin_k ||x_g - emb_k||^2][c].
//
// R4: fp32 GEMM + fused argmin, 8x8 register tile per lane
// (halves LDS instrs/fma vs R3's 4x4 -> VALU-bound, not LDS-bound).
// Block = 128 thr (2 waves), 128 positions; wave tile 64 pos x 64 k;
// lane = kl(8 k-groups) x pl(8 pos-groups). e_sq fused: computed from
// staging registers as 2 partials, summed at distance time (no 2nd kernel).

#define HWD  4096   // H*W
#define CD   64     // C == D
#define KD   512
#define PT   128    // positions per block
#define KT   64     // k per tile
#define XSTR 132    // xs row stride (pad: staging-write conflict reduction)

__launch_bounds__(128, 1)
__global__ void vq_main_kernel(const float* __restrict__ x,
                               const float* __restrict__ emb,
                               float* __restrict__ out) {
    const int tid  = threadIdx.x;
    const int lane = tid & 63;
    const int wv   = __builtin_amdgcn_readfirstlane(tid >> 6);  // 0/1
    const int kl   = lane & 7;    // k-group   [0,8) -> 8 codes each
    const int pl   = lane >> 3;   // pos-group [0,8) -> 8 positions each

    const int g0 = blockIdx.x << 7;   // 128 positions/block
    const int b  = g0 >> 12;          // 128 | 4096: no b straddle
    const int n0 = g0 & 4095;

    __shared__ __align__(16) float xs[CD][XSTR];   // 33792 B, [c][pos]
    __shared__ __align__(16) float es[CD][KT];     // 16384 B, [c][k]
    __shared__ float esq_p[2][KT];                 // e_sq halves
    __shared__ int   bk_s[PT];

    // ---- stage x tile [c][pos]: 2048 float4, 16 per thread, coalesced ----
    const float* xg = x + (size_t)b * (CD * HWD) + n0;
    #pragma unroll
    for (int i = 0; i < 16; ++i) {
        int fq = i * 128 + tid;
        int c  = fq >> 5;
        int q  = fq & 31;
        float4 v = *(const float4*)(xg + (size_t)c * HWD + q * 4);
        *(float4*)&xs[c][q * 4] = v;
    }

    const float* ap = &xs[0][wv * 64 + pl * 8];   // 8 positions (2-way bank, free)
    const float* bp = &es[0][kl * 8];             // 8 codes     (2-way bank, free)

    float bestd[8]; int bestk[8];
    #pragma unroll
    for (int p = 0; p < 8; ++p) { bestd[p] = FLT_MAX; bestk[p] = 0; }

    const int kk = tid & 63;   // emb staging: k row
    const int ch = tid >> 6;   // emb staging: c half (32 c each)

    for (int nt = 0; nt < KD / KT; ++nt) {
        __syncthreads();   // WAR: protect es/esq_p from previous tile readers

        // stage emb tile transposed es[c][k] <- emb[nt*64+k][c];
        // e_sq partial comes free from the staged registers
        {
            const float* eg = emb + (size_t)(nt * KT + kk) * CD + ch * 32;
            float s = 0.f;
            #pragma unroll
            for (int j = 0; j < 8; ++j) {
                float4 ev = *(const float4*)(eg + j * 4);
                int c0 = ch * 32 + j * 4;
                es[c0 + 0][kk] = ev.x;
                es[c0 + 1][kk] = ev.y;
                es[c0 + 2][kk] = ev.z;
                es[c0 + 3][kk] = ev.w;
                s = fmaf(ev.x, ev.x, fmaf(ev.y, ev.y,
                    fmaf(ev.z, ev.z, fmaf(ev.w, ev.w, s))));
            }
            esq_p[ch][kk] = s;
        }
        __syncthreads();

        float C[8][8];
        #pragma unroll
        for (int p = 0; p < 8; ++p)
            #pragma unroll
            for (int j = 0; j < 8; ++j) C[p][j] = 0.f;

        #pragma unroll 8   // keep loop body ~I-cache sized
        for (int c = 0; c < CD; ++c) {
            float4 a0 = *(const float4*)(ap + c * XSTR);
            float4 a1 = *(const float4*)(ap + c * XSTR + 4);
            float4 b0 = *(const float4*)(bp + c * KT);
            float4 b1 = *(const float4*)(bp + c * KT + 4);
            float av[8] = {a0.x, a0.y, a0.z, a0.w, a1.x, a1.y, a1.z, a1.w};
            float bv[8] = {b0.x, b0.y, b0.z, b0.w, b1.x, b1.y, b1.z, b1.w};
            #pragma unroll
            for (int p = 0; p < 8; ++p)
                #pragma unroll
                for (int j = 0; j < 8; ++j)
                    C[p][j] = fmaf(av[p], bv[j], C[p][j]);
        }

        // distances + running argmin (j ascending, strict <: lowest k on ties)
        float eq[8];
        #pragma unroll
        for (int j = 0; j < 8; ++j)
            eq[j] = esq_p[0][kl * 8 + j] + esq_p[1][kl * 8 + j];
        const int kb0 = nt * KT + kl * 8;
        #pragma unroll
        for (int p = 0; p < 8; ++p)
            #pragma unroll
            for (int j = 0; j < 8; ++j) {
                float d = fmaf(-2.f, C[p][j], eq[j]);
                if (d < bestd[p]) { bestd[p] = d; bestk[p] = kb0 + j; }
            }
    }

    // ---- cross-lane argmin over kl (bits 0..2), composite tie predicate ----
    #pragma unroll
    for (int m = 1; m <= 4; m <<= 1) {
        #pragma unroll
        for (int p = 0; p < 8; ++p) {
            float od = __shfl_xor(bestd[p], m, 64);
            int   ok = __shfl_xor(bestk[p], m, 64);
            bool take = (od < bestd[p]) || (od == bestd[p] && ok < bestk[p]);
            if (take) { bestd[p] = od; bestk[p] = ok; }
        }
    }
    if (kl == 0) {
        #pragma unroll
        for (int p = 0; p < 8; ++p)
            bk_s[wv * 64 + pl * 8 + p] = bestk[p];
    }
    __syncthreads();

    // ---- gather epilogue: wave-uniform rows, 256-B coalesced, batched ----
    const size_t ob = (size_t)g0 * CD;
    for (int it = 0; it < 64; it += 4) {
        float v[4]; int pp[4];
        #pragma unroll
        for (int j = 0; j < 4; ++j) {
            int p = (it + j) * 2 + wv;
            pp[j] = p;
            v[j]  = emb[bk_s[p] * CD + lane];   // L2-hot
        }
        #pragma unroll
        for (int j = 0; j < 4; ++j)
            out[ob + (size_t)pp[j] * CD + lane] = v[j];
    }
}

extern "C" void kernel_launch(void* const* d_in, const int* in_sizes, int n_in,
                              void* d_out, int out_size, void* d_ws, size_t ws_size,
                              hipStream_t stream) {
    const float* x   = (const float*)d_in[0];   // 32*64*64*64
    const float* emb = (const float*)d_in[1];   // 512*64
    float* out = (float*)d_out;                 // 8388608 floats

    vq_main_kernel<<<1024, 128, 0, stream>>>(x, emb, out);
}